// Round 11
// baseline (570.937 us; speedup 1.0000x reference)
//
#include <hip/hip_runtime.h>
#include <hip/hip_bf16.h>

using bf16 = __hip_bfloat16;
typedef __attribute__((ext_vector_type(8))) short bf16x8;
typedef __attribute__((ext_vector_type(4))) float f32x4;

__device__ __forceinline__ float lo2f(unsigned u) { return __uint_as_float(u << 16); }
__device__ __forceinline__ float hi2f(unsigned u) { return __uint_as_float(u & 0xffff0000u); }
__device__ __forceinline__ unsigned pack_bf2(float a, float b) {
    bf16 t0 = __float2bfloat16(a), t1 = __float2bfloat16(b);
    return (unsigned)*(unsigned short*)&t0 | ((unsigned)*(unsigned short*)&t1 << 16);
}

// -------- cast fp32 (bf16-valued) -> bf16, lossless --------
__global__ void cast_k(const float* __restrict__ in, int n, bf16* __restrict__ out) {
    int i = blockIdx.x * blockDim.x + threadIdx.x;
    if (i < n) out[i] = __float2bfloat16(in[i]);
}

// -------- degree histogram over dst --------
__global__ void hist_deg(const int* __restrict__ ei, int E, int* __restrict__ deg) {
    int e = blockIdx.x * blockDim.x + threadIdx.x;
    if (e < E) atomicAdd(&deg[ei[E + e]], 1);
}

__global__ void dinv_k(const int* __restrict__ deg, int N, float* __restrict__ dinv) {
    int v = blockIdx.x * blockDim.x + threadIdx.x;
    if (v < N) dinv[v] = rsqrtf((float)(deg[v] + 1));  // +1 self-loop
}

// -------- device-wide exclusive scan, 3 kernels --------
__global__ __launch_bounds__(256)
void scan1(const int* __restrict__ deg, int N, int* __restrict__ rowptr,
           int* __restrict__ bsum) {
    __shared__ int sm[256];
    int t = threadIdx.x;
    int i = blockIdx.x * 256 + t;
    int v = (i < N) ? deg[i] : 0;
    sm[t] = v;
    __syncthreads();
#pragma unroll
    for (int off = 1; off < 256; off <<= 1) {
        int x = (t >= off) ? sm[t - off] : 0;
        __syncthreads();
        sm[t] += x;
        __syncthreads();
    }
    if (i < N) rowptr[i] = sm[t] - v;
    if (t == 255) bsum[blockIdx.x] = sm[255];
}

__global__ __launch_bounds__(256)
void scan2(int* __restrict__ bsum, int B, int N, int* __restrict__ rowptr) {
    __shared__ int sm[256];
    int t = threadIdx.x;
    int v = (t < B) ? bsum[t] : 0;
    sm[t] = v;
    __syncthreads();
#pragma unroll
    for (int off = 1; off < 256; off <<= 1) {
        int x = (t >= off) ? sm[t - off] : 0;
        __syncthreads();
        sm[t] += x;
        __syncthreads();
    }
    if (t < B) bsum[t] = sm[t] - v;
    if (t == 255) rowptr[N] = sm[255];
}

__global__ __launch_bounds__(256)
void scan3(int N, const int* __restrict__ bsum, int* __restrict__ rowptr) {
    int i = blockIdx.x * 256 + threadIdx.x;
    if (i < N) rowptr[i] += bsum[blockIdx.x];
}

// -------- bucketed CSR build (kills the 17x write amplification of naive fill) --------
// Bucket = 64 consecutive dst nodes. bbase[b] = rowptr[64*b] (free, ranges contiguous).
#define BW 64
__global__ void bbase_k(const int* __restrict__ rowptr, int N, int NB,
                        int* __restrict__ bbase) {
    int b = blockIdx.x * blockDim.x + threadIdx.x;
    if (b <= NB) bbase[b] = rowptr[min(b * BW, N)];
}

// pass 1: append (s,d) to dst-bucket segment; ~782 active write fronts -> L2-merged
__global__ void bucket_scatter(const int* __restrict__ ei, int E,
                               const int* __restrict__ bbase, int* __restrict__ bcur,
                               int2* __restrict__ tmp) {
    int e = blockIdx.x * blockDim.x + threadIdx.x;
    if (e >= E) return;
    int s = ei[e];
    int d = ei[E + e];
    int b = d >> 6;
    int p = atomicAdd(&bcur[b], 1);
    tmp[bbase[b] + p] = make_int2(s, d);
}

// pass 2: one block per bucket; LDS cursors; col writes confined to ~4KB window
__global__ __launch_bounds__(256)
void bucket_fill(const int2* __restrict__ tmp, const int* __restrict__ bbase,
                 const int* __restrict__ rowptr, int* __restrict__ col) {
    __shared__ int lcur[BW];
    int b = blockIdx.x;
    if (threadIdx.x < BW) lcur[threadIdx.x] = 0;
    __syncthreads();
    int beg = bbase[b], end = bbase[b + 1];
    int v0 = b * BW;
    for (int i = beg + threadIdx.x; i < end; i += 256) {
        int2 sd = tmp[i];
        int p = atomicAdd(&lcur[sd.y - v0], 1);
        col[rowptr[sd.y] + p] = sd.x;
    }
}

// -------- MFMA GEMM: g[v,:] = dinv[v] * (h[v,:] @ W), bf16 in/out, fp32 accum --------
#define LDK 136
__global__ __launch_bounds__(256)
void gemm_mfma(const bf16* __restrict__ hin, const float* __restrict__ W,
               const float* __restrict__ dinv, int N, bf16* __restrict__ g)
{
    __shared__ short Wt[128 * LDK];
    for (int i = threadIdx.x; i < 128 * 128; i += 256) {
        int k = i >> 7, n = i & 127;
        bf16 b = __float2bfloat16(W[i]);   // exact: values are bf16-quantized
        Wt[n * LDK + k] = *(short*)&b;
    }
    __syncthreads();

    int wave = threadIdx.x >> 6;
    int lane = threadIdx.x & 63;
    int ln   = lane & 15;
    int quad = lane >> 4;
    int m0 = (blockIdx.x * 4 + wave) * 16;
    if (m0 >= N) return;

    int row = m0 + ln;
    if (row >= N) row = N - 1;
    const short* hrow = (const short*)hin + (size_t)row * 128;

    bf16x8 a[4];
#pragma unroll
    for (int kk = 0; kk < 4; ++kk)
        a[kk] = *(const bf16x8*)(hrow + kk * 32 + quad * 8);

    f32x4 c[8];
#pragma unroll
    for (int nt = 0; nt < 8; ++nt) c[nt] = (f32x4){0.f, 0.f, 0.f, 0.f};

#pragma unroll
    for (int kk = 0; kk < 4; ++kk) {
#pragma unroll
        for (int nt = 0; nt < 8; ++nt) {
            bf16x8 b = *(const bf16x8*)&Wt[(nt * 16 + ln) * LDK + kk * 32 + quad * 8];
            c[nt] = __builtin_amdgcn_mfma_f32_16x16x32_bf16(a[kk], b, c[nt], 0, 0, 0);
        }
    }

#pragma unroll
    for (int r = 0; r < 4; ++r) {
        int m = m0 + quad * 4 + r;
        if (m < N) {
            float dv = dinv[m];
#pragma unroll
            for (int nt = 0; nt < 8; ++nt) {
                bf16 val = __float2bfloat16(c[nt][r] * dv);
                ((unsigned short*)g)[(size_t)m * 128 + nt * 16 + ln] = *(unsigned short*)&val;
            }
        }
    }
}

// -------- gather: h[v] = [relu](dinv[v]*(g[v] + sum_in g[s]) + bias), bf16 g/h --------
__global__ __launch_bounds__(256)
void gather16(const bf16* __restrict__ g, const int* __restrict__ rowptr,
              const int* __restrict__ col, const float* __restrict__ dinv,
              const float* __restrict__ bias, int N, int do_relu, bf16* __restrict__ hout)
{
    int v = blockIdx.x * 4 + (threadIdx.x >> 6);
    if (v >= N) return;
    int lane = threadIdx.x & 63;
    const unsigned* gp = (const unsigned*)g;

    unsigned su = gp[(size_t)v * 64 + lane];
    float s0 = lo2f(su), s1 = hi2f(su);

    int beg = rowptr[v], end = rowptr[v + 1];
    int i = beg;
    for (; i + 4 <= end; i += 4) {
        int c0 = col[i], c1 = col[i + 1], c2 = col[i + 2], c3 = col[i + 3];
        unsigned u0 = gp[(size_t)c0 * 64 + lane];
        unsigned u1 = gp[(size_t)c1 * 64 + lane];
        unsigned u2 = gp[(size_t)c2 * 64 + lane];
        unsigned u3 = gp[(size_t)c3 * 64 + lane];
        s0 += lo2f(u0) + lo2f(u1) + lo2f(u2) + lo2f(u3);
        s1 += hi2f(u0) + hi2f(u1) + hi2f(u2) + hi2f(u3);
    }
    for (; i < end; ++i) {
        unsigned u = gp[(size_t)col[i] * 64 + lane];
        s0 += lo2f(u);
        s1 += hi2f(u);
    }
    float dv = dinv[v];
    float2 bb = ((const float2*)bias)[lane];
    float r0 = fmaf(dv, s0, bb.x);
    float r1 = fmaf(dv, s1, bb.y);
    if (do_relu) { r0 = fmaxf(r0, 0.f); r1 = fmaxf(r1, 0.f); }
    ((unsigned*)hout)[(size_t)v * 64 + lane] = pack_bf2(r0, r1);
}

// -------- graph boundaries from sorted batch --------
__global__ void bounds_k(const int* __restrict__ batch, int N, int G, int* __restrict__ gstart) {
    int v = blockIdx.x * blockDim.x + threadIdx.x;
    if (v >= N) return;
    int b = batch[v];
    int bprev = (v == 0) ? -1 : batch[v - 1];
    for (int q = bprev + 1; q <= b; ++q) gstart[q] = v;
    if (v == N - 1)
        for (int q = b + 1; q <= G; ++q) gstart[q] = N;
}

// -------- parallel mean pool --------
#define PCH 32
__global__ __launch_bounds__(128)
void pool_part(const bf16* __restrict__ h, const int* __restrict__ batch, int N,
               float* __restrict__ pooled)
{
    int c0 = blockIdx.x * PCH;
    if (c0 >= N) return;
    int f = threadIdx.x;
    int end = min(c0 + PCH, N);
    int cur = batch[c0];
    float acc = 0.f;
    for (int v = c0; v < end; ++v) {
        int b = batch[v];
        if (b != cur) {
            atomicAdd(&pooled[cur * 128 + f], acc);
            acc = 0.f;
            cur = b;
        }
        acc += __bfloat162float(h[(size_t)v * 128 + f]);
    }
    atomicAdd(&pooled[cur * 128 + f], acc);
}

__global__ void pool_div(const int* __restrict__ gstart, int G, float* __restrict__ pooled) {
    int t = blockIdx.x * blockDim.x + threadIdx.x;
    int gg = t >> 7;
    if (gg >= G) return;
    int f = t & 127;
    int c = gstart[gg + 1] - gstart[gg];
    pooled[gg * 128 + f] /= (float)(c > 0 ? c : 1);
}

// -------- MLP head (fp32, tiny) --------
__global__ __launch_bounds__(256)
void mlp1_k(const float* __restrict__ pooled, const float* __restrict__ Wm1,
            const float* __restrict__ bm1, float* __restrict__ out1)
{
    __shared__ float Ps[128];
    int gg = blockIdx.x, j = threadIdx.x;
    if (j < 128) Ps[j] = pooled[gg * 128 + j];
    __syncthreads();
    float s = 0.f;
#pragma unroll 4
    for (int k = 0; k < 128; ++k) s = fmaf(Ps[k], Wm1[k * 256 + j], s);
    s += bm1[j];
    out1[gg * 256 + j] = fmaxf(s, 0.f);
}

__global__ __launch_bounds__(768)
void mlp2_k(const float* __restrict__ out1, const float* __restrict__ Wm2,
            const float* __restrict__ bm2, float* __restrict__ out)
{
    __shared__ float Os[256];
    int gg = blockIdx.x, j = threadIdx.x;
    if (j < 256) Os[j] = out1[gg * 256 + j];
    __syncthreads();
    float s = 0.f;
#pragma unroll 4
    for (int k = 0; k < 256; ++k) s = fmaf(Os[k], Wm2[k * 768 + j], s);
    s += bm2[j];
    out[gg * 768 + j] = s;
}

extern "C" void kernel_launch(void* const* d_in, const int* in_sizes, int n_in,
                              void* d_out, int out_size, void* d_ws, size_t ws_size,
                              hipStream_t stream)
{
    const float* x     = (const float*)d_in[0];
    const int*   ei    = (const int*)d_in[1];   // [2,E] int32: src row then dst row
    const int*   batch = (const int*)d_in[2];
    const float *W1 = (const float*)d_in[3],  *bb1 = (const float*)d_in[4];
    const float *W2 = (const float*)d_in[5],  *bb2 = (const float*)d_in[6];
    const float *W3 = (const float*)d_in[7],  *bb3 = (const float*)d_in[8];
    const float *Wm1 = (const float*)d_in[9],  *bm1 = (const float*)d_in[10];
    const float *Wm2 = (const float*)d_in[11], *bm2 = (const float*)d_in[12];

    const int N = in_sizes[2];        // 50000
    const int E = in_sizes[1] / 2;    // 800000
    const int G = out_size / 768;     // 256
    const int NB = (N + BW - 1) / BW; // dst buckets (782)

    char* wp = (char*)d_ws;
    bf16* bufX   = (bf16*)wp;  wp += (size_t)N * 128 * 2;   // 12.8 MB
    bf16* bufG   = (bf16*)wp;  wp += (size_t)N * 128 * 2;   // 12.8 MB
    bf16* bufH   = (bf16*)wp;  wp += (size_t)N * 128 * 2;   // 12.8 MB
    int2* tmp    = (int2*)wp;  wp += (size_t)E * 8;         // 6.4 MB
    int*  col    = (int*)wp;   wp += (size_t)E * 4;         // 3.2 MB
    int*  rowptr = (int*)wp;   wp += (size_t)(N + 1) * 4;
    int*  deg    = (int*)wp;   wp += (size_t)N * 4;
    float* dinv  = (float*)wp; wp += (size_t)N * 4;
    int*  bbase  = (int*)wp;   wp += (size_t)(NB + 1) * 4;
    int*  bcur   = (int*)wp;   wp += (size_t)NB * 4;
    int*  gstart = (int*)wp;   wp += (size_t)(G + 1) * 4;
    float* pooled= (float*)wp; wp += (size_t)G * 128 * 4;
    float* out1  = (float*)wp; wp += (size_t)G * 256 * 4;
    int*  bsum   = (int*)wp;   wp += 256 * 4;

    hipMemsetAsync(deg, 0, (size_t)N * 4, stream);
    hipMemsetAsync(bcur, 0, (size_t)NB * 4, stream);
    hipMemsetAsync(pooled, 0, (size_t)G * 128 * 4, stream);

    const int SB = (N + 255) / 256;

    // graph structure + input cast
    hist_deg<<<(E + 255) / 256, 256, 0, stream>>>(ei, E, deg);
    dinv_k<<<(N + 255) / 256, 256, 0, stream>>>(deg, N, dinv);
    scan1<<<SB, 256, 0, stream>>>(deg, N, rowptr, bsum);
    scan2<<<1, 256, 0, stream>>>(bsum, SB, N, rowptr);
    scan3<<<SB, 256, 0, stream>>>(N, bsum, rowptr);
    bbase_k<<<(NB + 256) / 256, 256, 0, stream>>>(rowptr, N, NB, bbase);
    bucket_scatter<<<(E + 255) / 256, 256, 0, stream>>>(ei, E, bbase, bcur, tmp);
    bucket_fill<<<NB, 256, 0, stream>>>(tmp, bbase, rowptr, col);
    bounds_k<<<(N + 255) / 256, 256, 0, stream>>>(batch, N, G, gstart);
    cast_k<<<(N * 128 + 255) / 256, 256, 0, stream>>>(x, N * 128, bufX);

    const int gemm_grid   = (N + 63) / 64;
    const int gather_grid = (N + 3) / 4;

    // layer 1: bufX -> bufG -> bufH
    gemm_mfma<<<gemm_grid, 256, 0, stream>>>(bufX, W1, dinv, N, bufG);
    gather16<<<gather_grid, 256, 0, stream>>>(bufG, rowptr, col, dinv, bb1, N, 1, bufH);
    // layer 2: bufH -> bufG -> bufX (reuse)
    gemm_mfma<<<gemm_grid, 256, 0, stream>>>(bufH, W2, dinv, N, bufG);
    gather16<<<gather_grid, 256, 0, stream>>>(bufG, rowptr, col, dinv, bb2, N, 1, bufX);
    // layer 3 (no relu): bufX -> bufG -> bufH
    gemm_mfma<<<gemm_grid, 256, 0, stream>>>(bufX, W3, dinv, N, bufG);
    gather16<<<gather_grid, 256, 0, stream>>>(bufG, rowptr, col, dinv, bb3, N, 0, bufH);

    // parallel mean pool
    pool_part<<<(N + PCH - 1) / PCH, 128, 0, stream>>>(bufH, batch, N, pooled);
    pool_div<<<(G * 128 + 255) / 256, 256, 0, stream>>>(gstart, G, pooled);

    // MLP head
    mlp1_k<<<G, 256, 0, stream>>>(pooled, Wm1, bm1, out1);
    mlp2_k<<<G, 768, 0, stream>>>(out1, Wm2, bm2, (float*)d_out);
}

// Round 12
// 388.489 us; speedup vs baseline: 1.4696x; 1.4696x over previous
//
#include <hip/hip_runtime.h>
#include <hip/hip_bf16.h>

using bf16 = __hip_bfloat16;
typedef __attribute__((ext_vector_type(8))) short bf16x8;
typedef __attribute__((ext_vector_type(4))) float f32x4;

__device__ __forceinline__ float lo2f(unsigned u) { return __uint_as_float(u << 16); }
__device__ __forceinline__ float hi2f(unsigned u) { return __uint_as_float(u & 0xffff0000u); }
__device__ __forceinline__ unsigned pack_bf2(float a, float b) {
    bf16 t0 = __float2bfloat16(a), t1 = __float2bfloat16(b);
    return (unsigned)*(unsigned short*)&t0 | ((unsigned)*(unsigned short*)&t1 << 16);
}

// -------- cast fp32 (bf16-valued) -> bf16, lossless --------
__global__ void cast_k(const float* __restrict__ in, int n, bf16* __restrict__ out) {
    int i = blockIdx.x * blockDim.x + threadIdx.x;
    if (i < n) out[i] = __float2bfloat16(in[i]);
}

// -------- degree histogram over dst --------
__global__ void hist_deg(const int* __restrict__ ei, int E, int* __restrict__ deg) {
    int e = blockIdx.x * blockDim.x + threadIdx.x;
    if (e < E) atomicAdd(&deg[ei[E + e]], 1);
}

__global__ void dinv_k(const int* __restrict__ deg, int N, float* __restrict__ dinv) {
    int v = blockIdx.x * blockDim.x + threadIdx.x;
    if (v < N) dinv[v] = rsqrtf((float)(deg[v] + 1));  // +1 self-loop
}

// -------- device-wide exclusive scan, 3 kernels --------
__global__ __launch_bounds__(256)
void scan1(const int* __restrict__ deg, int N, int* __restrict__ rowptr,
           int* __restrict__ bsum) {
    __shared__ int sm[256];
    int t = threadIdx.x;
    int i = blockIdx.x * 256 + t;
    int v = (i < N) ? deg[i] : 0;
    sm[t] = v;
    __syncthreads();
#pragma unroll
    for (int off = 1; off < 256; off <<= 1) {
        int x = (t >= off) ? sm[t - off] : 0;
        __syncthreads();
        sm[t] += x;
        __syncthreads();
    }
    if (i < N) rowptr[i] = sm[t] - v;
    if (t == 255) bsum[blockIdx.x] = sm[255];
}

__global__ __launch_bounds__(256)
void scan2(int* __restrict__ bsum, int B, int N, int* __restrict__ rowptr) {
    __shared__ int sm[256];
    int t = threadIdx.x;
    int v = (t < B) ? bsum[t] : 0;
    sm[t] = v;
    __syncthreads();
#pragma unroll
    for (int off = 1; off < 256; off <<= 1) {
        int x = (t >= off) ? sm[t - off] : 0;
        __syncthreads();
        sm[t] += x;
        __syncthreads();
    }
    if (t < B) bsum[t] = sm[t] - v;
    if (t == 255) rowptr[N] = sm[255];
}

__global__ __launch_bounds__(256)
void scan3(int N, const int* __restrict__ bsum, int* __restrict__ rowptr) {
    int i = blockIdx.x * 256 + threadIdx.x;
    if (i < N) rowptr[i] += bsum[blockIdx.x];
}

// -------- CSR fill (naive; 50000 private write fronts beats shared-front bucketing
// on multi-XCD — R11 measured 3.5x regression from 782 shared fronts) --------
__global__ void fill_col(const int* __restrict__ ei, int E, const int* __restrict__ rowptr,
                         int* __restrict__ cursor, int* __restrict__ col) {
    int e = blockIdx.x * blockDim.x + threadIdx.x;
    if (e >= E) return;
    int s = ei[e];
    int d = ei[E + e];
    int p = atomicAdd(&cursor[d], 1);
    col[rowptr[d] + p] = s;
}

// -------- MFMA GEMM: g[v,:] = dinv[v] * (h[v,:] @ W), bf16 in/out, fp32 accum --------
#define LDK 136
__global__ __launch_bounds__(256)
void gemm_mfma(const bf16* __restrict__ hin, const float* __restrict__ W,
               const float* __restrict__ dinv, int N, bf16* __restrict__ g)
{
    __shared__ short Wt[128 * LDK];
    for (int i = threadIdx.x; i < 128 * 128; i += 256) {
        int k = i >> 7, n = i & 127;
        bf16 b = __float2bfloat16(W[i]);   // exact: values are bf16-quantized
        Wt[n * LDK + k] = *(short*)&b;
    }
    __syncthreads();

    int wave = threadIdx.x >> 6;
    int lane = threadIdx.x & 63;
    int ln   = lane & 15;
    int quad = lane >> 4;
    int m0 = (blockIdx.x * 4 + wave) * 16;
    if (m0 >= N) return;

    int row = m0 + ln;
    if (row >= N) row = N - 1;
    const short* hrow = (const short*)hin + (size_t)row * 128;

    bf16x8 a[4];
#pragma unroll
    for (int kk = 0; kk < 4; ++kk)
        a[kk] = *(const bf16x8*)(hrow + kk * 32 + quad * 8);

    f32x4 c[8];
#pragma unroll
    for (int nt = 0; nt < 8; ++nt) c[nt] = (f32x4){0.f, 0.f, 0.f, 0.f};

#pragma unroll
    for (int kk = 0; kk < 4; ++kk) {
#pragma unroll
        for (int nt = 0; nt < 8; ++nt) {
            bf16x8 b = *(const bf16x8*)&Wt[(nt * 16 + ln) * LDK + kk * 32 + quad * 8];
            c[nt] = __builtin_amdgcn_mfma_f32_16x16x32_bf16(a[kk], b, c[nt], 0, 0, 0);
        }
    }

#pragma unroll
    for (int r = 0; r < 4; ++r) {
        int m = m0 + quad * 4 + r;
        if (m < N) {
            float dv = dinv[m];
#pragma unroll
            for (int nt = 0; nt < 8; ++nt) {
                bf16 val = __float2bfloat16(c[nt][r] * dv);
                ((unsigned short*)g)[(size_t)m * 128 + nt * 16 + ln] = *(unsigned short*)&val;
            }
        }
    }
}

// -------- gather: h[v] = [relu](dinv[v]*(g[v] + sum_in g[s]) + bias), bf16 g/h --------
// one wave per node; edge loop unrolled x8 (8 outstanding row-reads per lane)
__global__ __launch_bounds__(256)
void gather16(const bf16* __restrict__ g, const int* __restrict__ rowptr,
              const int* __restrict__ col, const float* __restrict__ dinv,
              const float* __restrict__ bias, int N, int do_relu, bf16* __restrict__ hout)
{
    int v = blockIdx.x * 4 + (threadIdx.x >> 6);
    if (v >= N) return;
    int lane = threadIdx.x & 63;
    const unsigned* gp = (const unsigned*)g;

    unsigned su = gp[(size_t)v * 64 + lane];
    float s0 = lo2f(su), s1 = hi2f(su);

    int beg = rowptr[v], end = rowptr[v + 1];
    int i = beg;
    for (; i + 8 <= end; i += 8) {
        int cc[8];
#pragma unroll
        for (int j = 0; j < 8; ++j) cc[j] = col[i + j];
        unsigned uu[8];
#pragma unroll
        for (int j = 0; j < 8; ++j) uu[j] = gp[(size_t)cc[j] * 64 + lane];
#pragma unroll
        for (int j = 0; j < 8; ++j) { s0 += lo2f(uu[j]); s1 += hi2f(uu[j]); }
    }
    for (; i + 4 <= end; i += 4) {
        int c0 = col[i], c1 = col[i + 1], c2 = col[i + 2], c3 = col[i + 3];
        unsigned u0 = gp[(size_t)c0 * 64 + lane];
        unsigned u1 = gp[(size_t)c1 * 64 + lane];
        unsigned u2 = gp[(size_t)c2 * 64 + lane];
        unsigned u3 = gp[(size_t)c3 * 64 + lane];
        s0 += lo2f(u0) + lo2f(u1) + lo2f(u2) + lo2f(u3);
        s1 += hi2f(u0) + hi2f(u1) + hi2f(u2) + hi2f(u3);
    }
    for (; i < end; ++i) {
        unsigned u = gp[(size_t)col[i] * 64 + lane];
        s0 += lo2f(u);
        s1 += hi2f(u);
    }
    float dv = dinv[v];
    float2 bb = ((const float2*)bias)[lane];
    float r0 = fmaf(dv, s0, bb.x);
    float r1 = fmaf(dv, s1, bb.y);
    if (do_relu) { r0 = fmaxf(r0, 0.f); r1 = fmaxf(r1, 0.f); }
    ((unsigned*)hout)[(size_t)v * 64 + lane] = pack_bf2(r0, r1);
}

// -------- graph boundaries from sorted batch --------
__global__ void bounds_k(const int* __restrict__ batch, int N, int G, int* __restrict__ gstart) {
    int v = blockIdx.x * blockDim.x + threadIdx.x;
    if (v >= N) return;
    int b = batch[v];
    int bprev = (v == 0) ? -1 : batch[v - 1];
    for (int q = bprev + 1; q <= b; ++q) gstart[q] = v;
    if (v == N - 1)
        for (int q = b + 1; q <= G; ++q) gstart[q] = N;
}

// -------- parallel mean pool --------
#define PCH 32
__global__ __launch_bounds__(128)
void pool_part(const bf16* __restrict__ h, const int* __restrict__ batch, int N,
               float* __restrict__ pooled)
{
    int c0 = blockIdx.x * PCH;
    if (c0 >= N) return;
    int f = threadIdx.x;
    int end = min(c0 + PCH, N);
    int cur = batch[c0];
    float acc = 0.f;
    for (int v = c0; v < end; ++v) {
        int b = batch[v];
        if (b != cur) {
            atomicAdd(&pooled[cur * 128 + f], acc);
            acc = 0.f;
            cur = b;
        }
        acc += __bfloat162float(h[(size_t)v * 128 + f]);
    }
    atomicAdd(&pooled[cur * 128 + f], acc);
}

__global__ void pool_div(const int* __restrict__ gstart, int G, float* __restrict__ pooled) {
    int t = blockIdx.x * blockDim.x + threadIdx.x;
    int gg = t >> 7;
    if (gg >= G) return;
    int f = t & 127;
    int c = gstart[gg + 1] - gstart[gg];
    pooled[gg * 128 + f] /= (float)(c > 0 ? c : 1);
}

// -------- MLP head (fp32, tiny) --------
__global__ __launch_bounds__(256)
void mlp1_k(const float* __restrict__ pooled, const float* __restrict__ Wm1,
            const float* __restrict__ bm1, float* __restrict__ out1)
{
    __shared__ float Ps[128];
    int gg = blockIdx.x, j = threadIdx.x;
    if (j < 128) Ps[j] = pooled[gg * 128 + j];
    __syncthreads();
    float s = 0.f;
#pragma unroll 4
    for (int k = 0; k < 128; ++k) s = fmaf(Ps[k], Wm1[k * 256 + j], s);
    s += bm1[j];
    out1[gg * 256 + j] = fmaxf(s, 0.f);
}

__global__ __launch_bounds__(768)
void mlp2_k(const float* __restrict__ out1, const float* __restrict__ Wm2,
            const float* __restrict__ bm2, float* __restrict__ out)
{
    __shared__ float Os[256];
    int gg = blockIdx.x, j = threadIdx.x;
    if (j < 256) Os[j] = out1[gg * 256 + j];
    __syncthreads();
    float s = 0.f;
#pragma unroll 4
    for (int k = 0; k < 256; ++k) s = fmaf(Os[k], Wm2[k * 768 + j], s);
    s += bm2[j];
    out[gg * 768 + j] = s;
}

extern "C" void kernel_launch(void* const* d_in, const int* in_sizes, int n_in,
                              void* d_out, int out_size, void* d_ws, size_t ws_size,
                              hipStream_t stream)
{
    const float* x     = (const float*)d_in[0];
    const int*   ei    = (const int*)d_in[1];   // [2,E] int32: src row then dst row
    const int*   batch = (const int*)d_in[2];
    const float *W1 = (const float*)d_in[3],  *bb1 = (const float*)d_in[4];
    const float *W2 = (const float*)d_in[5],  *bb2 = (const float*)d_in[6];
    const float *W3 = (const float*)d_in[7],  *bb3 = (const float*)d_in[8];
    const float *Wm1 = (const float*)d_in[9],  *bm1 = (const float*)d_in[10];
    const float *Wm2 = (const float*)d_in[11], *bm2 = (const float*)d_in[12];

    const int N = in_sizes[2];        // 50000
    const int E = in_sizes[1] / 2;    // 800000
    const int G = out_size / 768;     // 256

    char* wp = (char*)d_ws;
    bf16* bufX   = (bf16*)wp;  wp += (size_t)N * 128 * 2;   // 12.8 MB
    bf16* bufG   = (bf16*)wp;  wp += (size_t)N * 128 * 2;   // 12.8 MB
    bf16* bufH   = (bf16*)wp;  wp += (size_t)N * 128 * 2;   // 12.8 MB
    int*  col    = (int*)wp;   wp += (size_t)E * 4;         // 3.2 MB
    int*  rowptr = (int*)wp;   wp += (size_t)(N + 1) * 4;
    int*  cursor = (int*)wp;   wp += (size_t)N * 4;
    int*  deg    = (int*)wp;   wp += (size_t)N * 4;
    float* dinv  = (float*)wp; wp += (size_t)N * 4;
    int*  gstart = (int*)wp;   wp += (size_t)(G + 1) * 4;
    float* pooled= (float*)wp; wp += (size_t)G * 128 * 4;
    float* out1  = (float*)wp; wp += (size_t)G * 256 * 4;
    int*  bsum   = (int*)wp;   wp += 256 * 4;

    hipMemsetAsync(deg, 0, (size_t)N * 4, stream);
    hipMemsetAsync(cursor, 0, (size_t)N * 4, stream);
    hipMemsetAsync(pooled, 0, (size_t)G * 128 * 4, stream);

    const int SB = (N + 255) / 256;

    // graph structure + input cast
    hist_deg<<<(E + 255) / 256, 256, 0, stream>>>(ei, E, deg);
    dinv_k<<<(N + 255) / 256, 256, 0, stream>>>(deg, N, dinv);
    scan1<<<SB, 256, 0, stream>>>(deg, N, rowptr, bsum);
    scan2<<<1, 256, 0, stream>>>(bsum, SB, N, rowptr);
    scan3<<<SB, 256, 0, stream>>>(N, bsum, rowptr);
    fill_col<<<(E + 255) / 256, 256, 0, stream>>>(ei, E, rowptr, cursor, col);
    bounds_k<<<(N + 255) / 256, 256, 0, stream>>>(batch, N, G, gstart);
    cast_k<<<(N * 128 + 255) / 256, 256, 0, stream>>>(x, N * 128, bufX);

    const int gemm_grid   = (N + 63) / 64;
    const int gather_grid = (N + 3) / 4;

    // layer 1: bufX -> bufG -> bufH
    gemm_mfma<<<gemm_grid, 256, 0, stream>>>(bufX, W1, dinv, N, bufG);
    gather16<<<gather_grid, 256, 0, stream>>>(bufG, rowptr, col, dinv, bb1, N, 1, bufH);
    // layer 2: bufH -> bufG -> bufX (reuse)
    gemm_mfma<<<gemm_grid, 256, 0, stream>>>(bufH, W2, dinv, N, bufG);
    gather16<<<gather_grid, 256, 0, stream>>>(bufG, rowptr, col, dinv, bb2, N, 1, bufX);
    // layer 3 (no relu): bufX -> bufG -> bufH
    gemm_mfma<<<gemm_grid, 256, 0, stream>>>(bufX, W3, dinv, N, bufG);
    gather16<<<gather_grid, 256, 0, stream>>>(bufG, rowptr, col, dinv, bb3, N, 0, bufH);

    // parallel mean pool
    pool_part<<<(N + PCH - 1) / PCH, 128, 0, stream>>>(bufH, batch, N, pooled);
    pool_div<<<(G * 128 + 255) / 256, 256, 0, stream>>>(gstart, G, pooled);

    // MLP head
    mlp1_k<<<G, 256, 0, stream>>>(pooled, Wm1, bm1, out1);
    mlp2_k<<<G, 768, 0, stream>>>(out1, Wm2, bm2, (float*)d_out);
}